// Round 4
// baseline (526.311 us; speedup 1.0000x reference)
//
#include <hip/hip_runtime.h>
#include <hip/hip_fp16.h>
#include <stdint.h>

#define B_ 2
#define C_ 96
#define D_ 24
#define H_ 56
#define W_ 56
#define E_ 384
#define HW_ (H_*W_)        // 3136
#define S_ (D_*HW_)        // 75264
#define N_ (B_*S_)         // 150528

typedef __attribute__((ext_vector_type(8))) short bf16x8;
typedef __attribute__((ext_vector_type(8))) unsigned short ushort8;
typedef __attribute__((ext_vector_type(4))) float f32x4;

static __device__ __forceinline__ float bf2f(unsigned short h){
    union { unsigned int u; float f; } v; v.u = ((unsigned int)h) << 16; return v.f;
}
static __device__ __forceinline__ unsigned short f2bf(float x){
    union { float f; unsigned int u; } v; v.f = x;
    unsigned int r = v.u + 0x7FFFu + ((v.u >> 16) & 1u);
    return (unsigned short)(r >> 16);
}
// fast GELU: v*sigmoid(1.5957691*(v+0.044715 v^3)) via exp2, max |err| ~3e-4
static __device__ __forceinline__ float gelu_f(float v){
    float v2 = v*v;
    float arg = v * fmaf(v2, -0.1029432f, -2.3022080f);
    return v / (1.f + exp2f(arg));
}

// ---------------- K1: depthwise 7x7x7 conv + bias -> ws1 (bf16, NCDHW) ----------
// tile 8d x 8h x 56w; halo 14x14x62 staged fp16, pitch 72 (28224 B LDS).
// thread: wz(0..6)*8 w-outputs, hz h-row, dz -> 2 consecutive d-outputs.
__global__ __launch_bounds__(256) void k1_dwconv(
    const float* __restrict__ x, const float* __restrict__ wk,
    const float* __restrict__ bias, unsigned short* __restrict__ ws1)
{
    __shared__ __align__(16) unsigned short hl[14*14*72];
    const int dt = blockIdx.x / 7;   // 0..2
    const int ht = blockIdx.x - dt*7;// 0..6
    const int c  = blockIdx.y, b = blockIdx.z;
    const int d0 = dt*8, h0 = ht*8;
    const int tid = threadIdx.x;
    const float* xc = x + (size_t)(b*C_ + c) * S_;

    for (int i = tid; i < 14*14*31; i += 256){
        int sidx = i / (14*31);
        int rem  = i - sidx*(14*31);
        int hr   = rem / 31;
        int wp   = rem - hr*31;
        int d = d0 - 3 + sidx, h = h0 - 3 + hr, w = wp*2 - 3;
        bool ok = (unsigned)d < D_ && (unsigned)h < H_;
        float v0 = (ok && (unsigned)w     < W_) ? xc[d*HW_ + h*W_ + w]   : 0.f;
        float v1 = (ok && (unsigned)(w+1) < W_) ? xc[d*HW_ + h*W_ + w+1] : 0.f;
        unsigned int pk = (unsigned)__half_as_ushort(__float2half(v0))
                        | ((unsigned)__half_as_ushort(__float2half(v1)) << 16);
        *(unsigned int*)&hl[(sidx*14 + hr)*72 + wp*2] = pk;
    }
    __syncthreads();

    const int wz = tid & 7, hz = (tid >> 3) & 7, dz = tid >> 6;
    if (wz >= 7) return;

    float acc0[8] = {0,0,0,0,0,0,0,0};
    float acc1[8] = {0,0,0,0,0,0,0,0};
    const float* wkc = wk + c*343;

    for (int si = 0; si < 8; ++si){
        const int rbase = (dz*2 + si)*14 + hz;
        for (int kh = 0; kh < 7; ++kh){
            const unsigned short* rp = &hl[(rbase + kh)*72 + wz*8];
            ushort8 u0 = *(const ushort8*)rp;
            ushort8 u1 = *(const ushort8*)(rp + 8);
            float win[14];
            #pragma unroll
            for (int j=0;j<8;++j) win[j]   = __half2float(__ushort_as_half(u0[j]));
            #pragma unroll
            for (int j=0;j<6;++j) win[8+j] = __half2float(__ushort_as_half(u1[j]));
            if (si < 7){
                const float* wr = wkc + si*49 + kh*7;
                #pragma unroll
                for (int kw=0;kw<7;++kw){
                    float wv = wr[kw];
                    #pragma unroll
                    for (int j=0;j<8;++j) acc0[j] = fmaf(win[kw+j], wv, acc0[j]);
                }
            }
            if (si > 0){
                const float* wr = wkc + (si-1)*49 + kh*7;
                #pragma unroll
                for (int kw=0;kw<7;++kw){
                    float wv = wr[kw];
                    #pragma unroll
                    for (int j=0;j<8;++j) acc1[j] = fmaf(win[kw+j], wv, acc1[j]);
                }
            }
        }
    }

    const float bs = bias[c];
    size_t o0 = (size_t)(b*C_ + c)*S_ + (size_t)(d0 + dz*2)*HW_ + (h0 + hz)*W_ + wz*8;
    unsigned int p0 = (unsigned)f2bf(acc0[0]+bs) | ((unsigned)f2bf(acc0[1]+bs)<<16);
    unsigned int p1 = (unsigned)f2bf(acc0[2]+bs) | ((unsigned)f2bf(acc0[3]+bs)<<16);
    unsigned int p2 = (unsigned)f2bf(acc0[4]+bs) | ((unsigned)f2bf(acc0[5]+bs)<<16);
    unsigned int p3 = (unsigned)f2bf(acc0[6]+bs) | ((unsigned)f2bf(acc0[7]+bs)<<16);
    *(uint4*)&ws1[o0] = make_uint4(p0,p1,p2,p3);
    p0 = (unsigned)f2bf(acc1[0]+bs) | ((unsigned)f2bf(acc1[1]+bs)<<16);
    p1 = (unsigned)f2bf(acc1[2]+bs) | ((unsigned)f2bf(acc1[3]+bs)<<16);
    p2 = (unsigned)f2bf(acc1[4]+bs) | ((unsigned)f2bf(acc1[5]+bs)<<16);
    p3 = (unsigned)f2bf(acc1[6]+bs) | ((unsigned)f2bf(acc1[7]+bs)<<16);
    *(uint4*)&ws1[o0 + HW_] = make_uint4(p0,p1,p2,p3);
}

// ---------- kw1t: w1 [C][E] f32 -> w1t [E][C] bf16 ------------------------------
__global__ __launch_bounds__(256) void kw1t(
    const float* __restrict__ w1, unsigned short* __restrict__ w1t)
{
    int idx = blockIdx.x*256 + threadIdx.x;
    if (idx < E_*C_){
        int e = idx / C_, c = idx % C_;
        w1t[idx] = f2bf(w1[c*E_ + e]);
    }
}

// ------------- K2: LayerNorm + pwconv1(MFMA) + GELU -> ws2 bf16 [N][E] ----------
__global__ __launch_bounds__(256) void k2_ln_pw1(
    const unsigned short* __restrict__ ws1, const float* __restrict__ ln_w,
    const float* __restrict__ ln_b, const unsigned short* __restrict__ w1t,
    const float* __restrict__ b1, unsigned short* __restrict__ ws2)
{
    __shared__ unsigned short ly[64*104];
    __shared__ float red1[256], red2[256];
    __shared__ float smu[64], srs[64];
    const int tid = threadIdx.x;
    const int p = tid & 63, q = tid >> 6;
    const int n0 = blockIdx.x * 64;
    const int b = n0 / S_;
    const int s0 = n0 - b*S_;
    const size_t basein = (size_t)(b*C_)*S_ + s0 + p;

    float v[24];
    float sum=0.f, ssq=0.f;
    #pragma unroll
    for (int i=0;i<24;++i){
        int c = q*24 + i;
        float t = bf2f(ws1[basein + (size_t)c*S_]);
        v[i] = t; sum += t; ssq = fmaf(t,t,ssq);
    }
    red1[tid]=sum; red2[tid]=ssq;
    __syncthreads();
    if (q==0){
        float s1 = red1[p]+red1[64+p]+red1[128+p]+red1[192+p];
        float s2 = red2[p]+red2[64+p]+red2[128+p]+red2[192+p];
        float mu = s1 * (1.f/96.f);
        float var = s2*(1.f/96.f) - mu*mu;
        smu[p]=mu; srs[p]=rsqrtf(var + 1e-6f);
    }
    __syncthreads();
    {
        float mu = smu[p], rs = srs[p];
        #pragma unroll
        for (int i=0;i<24;++i){
            int c = q*24+i;
            ly[p*104 + c] = f2bf((v[i]-mu)*rs*ln_w[c] + ln_b[c]);
        }
    }
    __syncthreads();

    const int lane = tid & 63;
    const int lr = lane & 15;
    const int lk = lane >> 4;
    bf16x8 af[3];
    #pragma unroll
    for (int kk=0;kk<3;++kk)
        af[kk] = *(const bf16x8*)&ly[(q*16 + lr)*104 + kk*32 + lk*8];

    for (int nt=0; nt<24; ++nt){
        f32x4 acc = {0.f,0.f,0.f,0.f};
        #pragma unroll
        for (int kk=0;kk<3;++kk){
            bf16x8 bfr = *(const bf16x8*)&w1t[(size_t)(nt*16 + lr)*C_ + kk*32 + lk*8];
            acc = __builtin_amdgcn_mfma_f32_16x16x32_bf16(af[kk], bfr, acc, 0, 0, 0);
        }
        float bias = b1[nt*16 + lr];
        #pragma unroll
        for (int r=0;r<4;++r){
            float val = acc[r] + bias;
            float g = gelu_f(val);
            int pos = q*16 + lk*4 + r;
            ws2[(size_t)(n0 + pos)*E_ + nt*16 + lr] = f2bf(g);
        }
    }
}

// ---------- K3a: GRN partial sum of squares, ws2 is [N][E] ----------------------
// chunk = 512 rows; thread t owns e = 2t,2t+1 (uint load = 2 bf16).
__global__ __launch_bounds__(192) void k3a1(
    const unsigned short* __restrict__ ws2, float* __restrict__ partial)
{
    const int chunk = blockIdx.x, b = blockIdx.y;    // 147 x 2
    const uint32_t* base = (const uint32_t*)(ws2 + ((size_t)b*S_ + (size_t)chunk*512)*E_);
    const int t = threadIdx.x;
    float a0=0.f, a1=0.f;
    #pragma unroll 4
    for (int r=0;r<512;++r){
        uint32_t u = base[(size_t)r*192 + t];
        float f0 = __uint_as_float(u << 16);
        float f1 = __uint_as_float(u & 0xFFFF0000u);
        a0 = fmaf(f0,f0,a0); a1 = fmaf(f1,f1,a1);
    }
    float* dst = partial + ((size_t)(b*147 + chunk))*E_;
    dst[2*t] = a0; dst[2*t+1] = a1;
}

// ---------- K3: reduce partials -> GRN scale -> w2s (bf16) + bc -----------------
__global__ __launch_bounds__(384) void k3_fuse(
    const float* __restrict__ partial, const float* __restrict__ gamma,
    const float* __restrict__ beta, const float* __restrict__ w2,
    const float* __restrict__ b2, unsigned short* __restrict__ w2s,
    float* __restrict__ bc)
{
    const int b = blockIdx.x, e = threadIdx.x;
    const float* p = partial + (size_t)b*147*384 + e;
    float s = 0.f;
    for (int i=0;i<147;++i) s += p[(size_t)i*384];
    float g = sqrtf(s);
    float vsum = g;
    #pragma unroll
    for (int off=32; off; off>>=1) vsum += __shfl_down(vsum, off);
    __shared__ float r[6];
    __shared__ float mean_s;
    if ((e & 63)==0) r[e>>6] = vsum;
    __syncthreads();
    if (e==0) mean_s = (r[0]+r[1]+r[2]+r[3]+r[4]+r[5]) * (1.f/384.f);
    __syncthreads();
    float sc = 1.f + gamma[e] * (g / (mean_s + 1e-6f));
    for (int c=0;c<96;++c)
        w2s[((size_t)b*C_ + c)*E_ + e] = f2bf(w2[e*C_ + c] * sc);
    if (b==0 && e<96){
        float a = b2[e];
        for (int k=0;k<E_;++k) a = fmaf(beta[k], w2[k*C_ + e], a);
        bc[e] = a;
    }
}

// ---------- K4: pwconv2 (MFMA, GRN folded in w2s) + bias + residual -------------
// B-frag read direct from global (ws2 row-major [pos][e] == [n][k]).
__global__ __launch_bounds__(256) void k4_pw2(
    const unsigned short* __restrict__ ws2, const unsigned short* __restrict__ w2s,
    const float* __restrict__ bc, const float* __restrict__ x,
    float* __restrict__ out)
{
    const int tid = threadIdx.x;
    const int n0 = blockIdx.x * 64;
    const int b = n0 / S_;
    const int s0 = n0 - b*S_;
    const int lane = tid & 63, q = tid >> 6;
    const int lr = lane & 15, lk = lane >> 4;

    f32x4 acc[6];
    #pragma unroll
    for (int m=0;m<6;++m) acc[m] = (f32x4){0.f,0.f,0.f,0.f};
    const unsigned short* w2sb = w2s + (size_t)b*C_*E_;
    const unsigned short* brow = ws2 + (size_t)(n0 + q*16 + lr)*E_;

    for (int kk=0; kk<12; ++kk){
        bf16x8 bfr = *(const bf16x8*)&brow[kk*32 + lk*8];
        #pragma unroll
        for (int m=0;m<6;++m){
            bf16x8 afr = *(const bf16x8*)&w2sb[(size_t)(m*16 + lr)*E_ + kk*32 + lk*8];
            acc[m] = __builtin_amdgcn_mfma_f32_16x16x32_bf16(afr, bfr, acc[m], 0, 0, 0);
        }
    }

    const int pos = q*16 + lr;
    const size_t sidx = (size_t)s0 + pos;
    #pragma unroll
    for (int m=0;m<6;++m){
        #pragma unroll
        for (int r=0;r<4;++r){
            int c = m*16 + lk*4 + r;
            size_t a = ((size_t)(b*C_ + c))*S_ + sidx;
            out[a] = acc[m][r] + bc[c] + x[a];
        }
    }
}

extern "C" void kernel_launch(void* const* d_in, const int* in_sizes, int n_in,
                              void* d_out, int out_size, void* d_ws, size_t ws_size,
                              hipStream_t stream)
{
    const float* x     = (const float*)d_in[0];
    const float* dwk   = (const float*)d_in[1];
    const float* dwb   = (const float*)d_in[2];
    const float* ln_w  = (const float*)d_in[3];
    const float* ln_b  = (const float*)d_in[4];
    const float* w1    = (const float*)d_in[5];
    const float* b1    = (const float*)d_in[6];
    const float* gamma = (const float*)d_in[7];
    const float* beta  = (const float*)d_in[8];
    const float* w2    = (const float*)d_in[9];
    const float* b2    = (const float*)d_in[10];
    float* out = (float*)d_out;

    char* ws = (char*)d_ws;
    unsigned short* ws1 = (unsigned short*)ws;                        // 57,802,752 B
    unsigned short* ws2 = (unsigned short*)(ws + 57802752);           // 115,605,504 B
    unsigned short* w1t = (unsigned short*)(ws + 173408256);          // 73,728 B
    // aliased into ws1 region (ws1 dead after k2; these written after k2):
    unsigned short* w2s = (unsigned short*)ws;                        // 294,912 B
    float* bc      = (float*)(ws + 294912);                           // 384 B
    float* partial = (float*)(ws + 1048576);                          // 451,584 B

    k1_dwconv <<<dim3(21,96,2), 256, 0, stream>>>(x, dwk, dwb, ws1);
    kw1t      <<<dim3(144),     256, 0, stream>>>(w1, w1t);
    k2_ln_pw1 <<<dim3(N_/64),   256, 0, stream>>>(ws1, ln_w, ln_b, w1t, b1, ws2);
    k3a1      <<<dim3(147,2),   192, 0, stream>>>(ws2, partial);
    k3_fuse   <<<dim3(2),       384, 0, stream>>>(partial, gamma, beta, w2, b2, w2s, bc);
    k4_pw2    <<<dim3(N_/64),   256, 0, stream>>>(ws2, w2s, bc, x, out);
}

// Round 6
// 426.859 us; speedup vs baseline: 1.2330x; 1.2330x over previous
//
#include <hip/hip_runtime.h>
#include <hip/hip_fp16.h>
#include <stdint.h>

#define B_ 2
#define C_ 96
#define D_ 24
#define H_ 56
#define W_ 56
#define E_ 384
#define HW_ (H_*W_)        // 3136
#define S_ (D_*HW_)        // 75264
#define N_ (B_*S_)         // 150528

typedef __attribute__((ext_vector_type(8))) short bf16x8;
typedef __attribute__((ext_vector_type(4))) float f32x4;

static __device__ __forceinline__ float bf2f(unsigned short h){
    union { unsigned int u; float f; } v; v.u = ((unsigned int)h) << 16; return v.f;
}
static __device__ __forceinline__ unsigned short f2bf(float x){
    union { float f; unsigned int u; } v; v.f = x;
    unsigned int r = v.u + 0x7FFFu + ((v.u >> 16) & 1u);
    return (unsigned short)(r >> 16);
}
static __device__ __forceinline__ __half2 u2h2(unsigned int u){
    union { unsigned int u; __half2 h; } v; v.u = u; return v.h;
}
// fast GELU: v*sigmoid(1.5957691*(v+0.044715 v^3)) via exp2, max |err| ~3e-4
static __device__ __forceinline__ float gelu_f(float v){
    float v2 = v*v;
    float arg = v * fmaf(v2, -0.1029432f, -2.3022080f);
    return v / (1.f + exp2f(arg));
}

// ---------------- K1: depthwise 7x7x7 conv + bias -> ws1 (bf16, NCDHW) ----------
// tile 8d x 8h x 56w; halo 14x14x62 staged fp16 (pitch 72). Packed v_pk_fma_f16:
// acc half2[4] = 8 w-outputs; weights pre-packed half2(w,w) in LDS; si-carry of
// previous weight row; odd taps via alignbit-shifted window.
__global__ __launch_bounds__(256) void k1_dwconv(
    const float* __restrict__ x, const float* __restrict__ wk,
    const float* __restrict__ bias, unsigned short* __restrict__ ws1)
{
    __shared__ __align__(16) unsigned short hl[14*14*72];
    __shared__ unsigned int pkw[344];
    const int dt = blockIdx.x / 7;   // 0..2
    const int ht = blockIdx.x - dt*7;// 0..6
    const int c  = blockIdx.y, b = blockIdx.z;
    const int d0 = dt*8, h0 = ht*8;
    const int tid = threadIdx.x;
    const float* xc = x + (size_t)(b*C_ + c) * S_;
    const float* wkc = wk + c*343;

    for (int i = tid; i < 343; i += 256){
        unsigned short us = __half_as_ushort(__float2half(wkc[i]));
        pkw[i] = (unsigned)us | ((unsigned)us << 16);
    }
    for (int i = tid; i < 14*14*31; i += 256){
        int sidx = i / (14*31);
        int rem  = i - sidx*(14*31);
        int hr   = rem / 31;
        int wp   = rem - hr*31;
        int d = d0 - 3 + sidx, h = h0 - 3 + hr, w = wp*2 - 3;
        bool ok = (unsigned)d < D_ && (unsigned)h < H_;
        float v0 = (ok && (unsigned)w     < W_) ? xc[d*HW_ + h*W_ + w]   : 0.f;
        float v1 = (ok && (unsigned)(w+1) < W_) ? xc[d*HW_ + h*W_ + w+1] : 0.f;
        unsigned int pk = (unsigned)__half_as_ushort(__float2half(v0))
                        | ((unsigned)__half_as_ushort(__float2half(v1)) << 16);
        *(unsigned int*)&hl[(sidx*14 + hr)*72 + wp*2] = pk;
    }
    __syncthreads();

    const int wz = tid & 7, hz = (tid >> 3) & 7, dz = tid >> 6;
    if (wz >= 7) return;

    __half2 acc0[4], acc1[4];
    #pragma unroll
    for (int r=0;r<4;++r){ acc0[r] = u2h2(0u); acc1[r] = u2h2(0u); }

    for (int kh = 0; kh < 7; ++kh){
        unsigned int wprev[7];
        for (int si = 0; si < 8; ++si){
            const unsigned short* rp = &hl[((dz*2 + si)*14 + hz + kh)*72 + wz*8];
            uint4 wa = *(const uint4*)rp;
            uint2 wb = *(const uint2*)(rp + 8);
            unsigned int wcq = *(const unsigned int*)(rp + 12);
            unsigned int W[7] = {wa.x, wa.y, wa.z, wa.w, wb.x, wb.y, wcq};
            unsigned int Sh[6];
            #pragma unroll
            for (int m=0;m<6;++m) Sh[m] = __builtin_amdgcn_alignbit(W[m+1], W[m], 16);

            if (si < 7){
                unsigned int wcur[7];
                #pragma unroll
                for (int k=0;k<7;++k) wcur[k] = pkw[si*49 + kh*7 + k];
                #pragma unroll
                for (int kw=0; kw<7; ++kw){
                    const int m = kw >> 1;
                    __half2 wp = u2h2(wcur[kw]);
                    #pragma unroll
                    for (int r=0;r<4;++r){
                        __half2 src = (kw & 1) ? u2h2(Sh[m+r]) : u2h2(W[m+r]);
                        acc0[r] = __hfma2(src, wp, acc0[r]);
                    }
                }
                if (si > 0){
                    #pragma unroll
                    for (int kw=0; kw<7; ++kw){
                        const int m = kw >> 1;
                        __half2 wp = u2h2(wprev[kw]);
                        #pragma unroll
                        for (int r=0;r<4;++r){
                            __half2 src = (kw & 1) ? u2h2(Sh[m+r]) : u2h2(W[m+r]);
                            acc1[r] = __hfma2(src, wp, acc1[r]);
                        }
                    }
                }
                #pragma unroll
                for (int k=0;k<7;++k) wprev[k] = wcur[k];
            } else {
                #pragma unroll
                for (int kw=0; kw<7; ++kw){
                    const int m = kw >> 1;
                    __half2 wp = u2h2(wprev[kw]);
                    #pragma unroll
                    for (int r=0;r<4;++r){
                        __half2 src = (kw & 1) ? u2h2(Sh[m+r]) : u2h2(W[m+r]);
                        acc1[r] = __hfma2(src, wp, acc1[r]);
                    }
                }
            }
        }
    }

    const float bs = bias[c];
    float o0v[8], o1v[8];
    #pragma unroll
    for (int r=0;r<4;++r){
        o0v[2*r]   = __low2float(acc0[r])  + bs;
        o0v[2*r+1] = __high2float(acc0[r]) + bs;
        o1v[2*r]   = __low2float(acc1[r])  + bs;
        o1v[2*r+1] = __high2float(acc1[r]) + bs;
    }
    size_t o0 = (size_t)(b*C_ + c)*S_ + (size_t)(d0 + dz*2)*HW_ + (h0 + hz)*W_ + wz*8;
    unsigned int p0 = (unsigned)f2bf(o0v[0]) | ((unsigned)f2bf(o0v[1])<<16);
    unsigned int p1 = (unsigned)f2bf(o0v[2]) | ((unsigned)f2bf(o0v[3])<<16);
    unsigned int p2 = (unsigned)f2bf(o0v[4]) | ((unsigned)f2bf(o0v[5])<<16);
    unsigned int p3 = (unsigned)f2bf(o0v[6]) | ((unsigned)f2bf(o0v[7])<<16);
    *(uint4*)&ws1[o0] = make_uint4(p0,p1,p2,p3);
    p0 = (unsigned)f2bf(o1v[0]) | ((unsigned)f2bf(o1v[1])<<16);
    p1 = (unsigned)f2bf(o1v[2]) | ((unsigned)f2bf(o1v[3])<<16);
    p2 = (unsigned)f2bf(o1v[4]) | ((unsigned)f2bf(o1v[5])<<16);
    p3 = (unsigned)f2bf(o1v[6]) | ((unsigned)f2bf(o1v[7])<<16);
    *(uint4*)&ws1[o0 + HW_] = make_uint4(p0,p1,p2,p3);
}

// ---------- kw1t: w1 [C][E] f32 -> w1t [E][C] bf16 ------------------------------
__global__ __launch_bounds__(256) void kw1t(
    const float* __restrict__ w1, unsigned short* __restrict__ w1t)
{
    int idx = blockIdx.x*256 + threadIdx.x;
    if (idx < E_*C_){
        int e = idx / C_, c = idx % C_;
        w1t[idx] = f2bf(w1[c*E_ + e]);
    }
}

// ------------- K2: LayerNorm + pwconv1(MFMA) + GELU -> ws2 bf16 [N][E] ----------
// + fused GRN sum-of-squares partials (written into d_out scratch region).
__global__ __launch_bounds__(256) void k2_ln_pw1(
    const unsigned short* __restrict__ ws1, const float* __restrict__ ln_w,
    const float* __restrict__ ln_b, const unsigned short* __restrict__ w1t,
    const float* __restrict__ b1, unsigned short* __restrict__ ws2,
    float* __restrict__ partial)
{
    __shared__ unsigned short ly[64*104];
    __shared__ float red1[256], red2[256];
    __shared__ float smu[64], srs[64];
    __shared__ float sq[4][384];
    const int tid = threadIdx.x;
    const int p = tid & 63, q = tid >> 6;
    const int n0 = blockIdx.x * 64;
    const int b = n0 / S_;
    const int s0 = n0 - b*S_;
    const size_t basein = (size_t)(b*C_)*S_ + s0 + p;

    float v[24];
    float sum=0.f, ssq=0.f;
    #pragma unroll
    for (int i=0;i<24;++i){
        int c = q*24 + i;
        float t = bf2f(ws1[basein + (size_t)c*S_]);
        v[i] = t; sum += t; ssq = fmaf(t,t,ssq);
    }
    red1[tid]=sum; red2[tid]=ssq;
    __syncthreads();
    if (q==0){
        float s1 = red1[p]+red1[64+p]+red1[128+p]+red1[192+p];
        float s2 = red2[p]+red2[64+p]+red2[128+p]+red2[192+p];
        float mu = s1 * (1.f/96.f);
        float var = s2*(1.f/96.f) - mu*mu;
        smu[p]=mu; srs[p]=rsqrtf(var + 1e-6f);
    }
    __syncthreads();
    {
        float mu = smu[p], rs = srs[p];
        #pragma unroll
        for (int i=0;i<24;++i){
            int c = q*24+i;
            ly[p*104 + c] = f2bf((v[i]-mu)*rs*ln_w[c] + ln_b[c]);
        }
    }
    __syncthreads();

    const int lane = tid & 63;
    const int lr = lane & 15;
    const int lk = lane >> 4;
    bf16x8 af[3];
    #pragma unroll
    for (int kk=0;kk<3;++kk)
        af[kk] = *(const bf16x8*)&ly[(q*16 + lr)*104 + kk*32 + lk*8];

    for (int nt=0; nt<24; ++nt){
        f32x4 acc = {0.f,0.f,0.f,0.f};
        #pragma unroll
        for (int kk=0;kk<3;++kk){
            bf16x8 bfr = *(const bf16x8*)&w1t[(size_t)(nt*16 + lr)*C_ + kk*32 + lk*8];
            acc = __builtin_amdgcn_mfma_f32_16x16x32_bf16(af[kk], bfr, acc, 0, 0, 0);
        }
        float bias = b1[nt*16 + lr];
        float ps = 0.f;
        #pragma unroll
        for (int r=0;r<4;++r){
            float val = acc[r] + bias;
            float g = gelu_f(val);
            ps = fmaf(g,g,ps);
            int pos = q*16 + lk*4 + r;
            ws2[(size_t)(n0 + pos)*E_ + nt*16 + lr] = f2bf(g);
        }
        ps += __shfl_xor(ps, 16);
        ps += __shfl_xor(ps, 32);
        if (lane < 16) sq[q][nt*16 + lane] = ps;
    }
    __syncthreads();
    // FIX (round-5 NaN): block has 256 threads but 384 slots — stride the loop.
    for (int i = tid; i < 384; i += 256)
        partial[(size_t)blockIdx.x*384 + i] = sq[0][i]+sq[1][i]+sq[2][i]+sq[3][i];
}

// ---------- K3: reduce partials -> GRN scale -> w2s (bf16) + bc -----------------
__global__ __launch_bounds__(384) void k3_fuse(
    const float* __restrict__ partial, const float* __restrict__ gamma,
    const float* __restrict__ beta, const float* __restrict__ w2,
    const float* __restrict__ b2, unsigned short* __restrict__ w2s,
    float* __restrict__ bc)
{
    const int b = blockIdx.x, e = threadIdx.x;
    const float* p = partial + (size_t)b*1176*384 + e;
    float s = 0.f;
    for (int i=0;i<1176;++i) s += p[(size_t)i*384];
    s = fmaxf(s, 0.f);                      // NaN insurance
    float g = sqrtf(s);
    float vsum = g;
    #pragma unroll
    for (int off=32; off; off>>=1) vsum += __shfl_down(vsum, off);
    __shared__ float r[6];
    __shared__ float mean_s;
    if ((e & 63)==0) r[e>>6] = vsum;
    __syncthreads();
    if (e==0) mean_s = (r[0]+r[1]+r[2]+r[3]+r[4]+r[5]) * (1.f/384.f);
    __syncthreads();
    float sc = 1.f + gamma[e] * (g / (mean_s + 1e-6f));
    for (int c=0;c<96;++c)
        w2s[((size_t)b*C_ + c)*E_ + e] = f2bf(w2[e*C_ + c] * sc);
    if (b==0 && e<96){
        float a = b2[e];
        for (int k=0;k<E_;++k) a = fmaf(beta[k], w2[k*C_ + e], a);
        bc[e] = a;
    }
}

// ---------- K4: pwconv2 (MFMA, GRN folded in w2s) + bias + residual -------------
__global__ __launch_bounds__(256) void k4_pw2(
    const unsigned short* __restrict__ ws2, const unsigned short* __restrict__ w2s,
    const float* __restrict__ bc, const float* __restrict__ x,
    float* __restrict__ out)
{
    const int tid = threadIdx.x;
    const int n0 = blockIdx.x * 64;
    const int b = n0 / S_;
    const int s0 = n0 - b*S_;
    const int lane = tid & 63, q = tid >> 6;
    const int lr = lane & 15, lk = lane >> 4;

    f32x4 acc[6];
    #pragma unroll
    for (int m=0;m<6;++m) acc[m] = (f32x4){0.f,0.f,0.f,0.f};
    const unsigned short* w2sb = w2s + (size_t)b*C_*E_;
    const unsigned short* brow = ws2 + (size_t)(n0 + q*16 + lr)*E_;

    for (int kk=0; kk<12; ++kk){
        bf16x8 bfr = *(const bf16x8*)&brow[kk*32 + lk*8];
        #pragma unroll
        for (int m=0;m<6;++m){
            bf16x8 afr = *(const bf16x8*)&w2sb[(size_t)(m*16 + lr)*E_ + kk*32 + lk*8];
            acc[m] = __builtin_amdgcn_mfma_f32_16x16x32_bf16(afr, bfr, acc[m], 0, 0, 0);
        }
    }

    const int pos = q*16 + lr;
    const size_t sidx = (size_t)s0 + pos;
    #pragma unroll
    for (int m=0;m<6;++m){
        #pragma unroll
        for (int r=0;r<4;++r){
            int c = m*16 + lk*4 + r;
            size_t a = ((size_t)(b*C_ + c))*S_ + sidx;
            out[a] = acc[m][r] + bc[c] + x[a];
        }
    }
}

extern "C" void kernel_launch(void* const* d_in, const int* in_sizes, int n_in,
                              void* d_out, int out_size, void* d_ws, size_t ws_size,
                              hipStream_t stream)
{
    const float* x     = (const float*)d_in[0];
    const float* dwk   = (const float*)d_in[1];
    const float* dwb   = (const float*)d_in[2];
    const float* ln_w  = (const float*)d_in[3];
    const float* ln_b  = (const float*)d_in[4];
    const float* w1    = (const float*)d_in[5];
    const float* b1    = (const float*)d_in[6];
    const float* gamma = (const float*)d_in[7];
    const float* beta  = (const float*)d_in[8];
    const float* w2    = (const float*)d_in[9];
    const float* b2    = (const float*)d_in[10];
    float* out = (float*)d_out;

    char* ws = (char*)d_ws;
    unsigned short* ws1 = (unsigned short*)ws;                        // 28,901,376 B used
    unsigned short* ws2 = (unsigned short*)(ws + 57802752);           // 115,605,504 B
    unsigned short* w1t = (unsigned short*)(ws + 173408256);          // 73,728 B
    // aliased into ws1 region (ws1 dead after k2; these written after k2):
    unsigned short* w2s = (unsigned short*)ws;                        // 294,912 B
    float* bc      = (float*)(ws + 294912);                           // 384 B
    // GRN partials live in the d_out region (k4 fully overwrites it afterwards):
    float* partial = (float*)d_out;                                   // 3,612,672 B

    k1_dwconv <<<dim3(21,96,2), 256, 0, stream>>>(x, dwk, dwb, ws1);
    kw1t      <<<dim3(144),     256, 0, stream>>>(w1, w1t);
    k2_ln_pw1 <<<dim3(N_/64),   256, 0, stream>>>(ws1, ln_w, ln_b, w1t, b1, ws2, partial);
    k3_fuse   <<<dim3(2),       384, 0, stream>>>(partial, gamma, beta, w2, b2, w2s, bc);
    k4_pw2    <<<dim3(N_/64),   256, 0, stream>>>(ws2, w2s, bc, x, out);
}